// Round 2
// baseline (83.106 us; speedup 1.0000x reference)
//
#include <hip/hip_runtime.h>
#include <hip/hip_bf16.h>
#include <stdint.h>

// out[b,j] = sum_{i,k} softmax(alphas[i,j,:])[k] * coeffs[i,j,k] * prim_k(x[b,i])
//         == P @ W2,  P[b, kg] = prim_op(x[b,i]),  W2[kg][j]
// k-ordering remapped so the MFMA A-fragment is one cacheline/lane:
//   kg = c*32 + quad*8 + j  <->  i = quad*16 + c , op = j   (c=0..15, quad=0..3)
//
// R7: TWO-KERNEL SPLIT — kill per-block W2 redundancy and the barrier.
//  - K1 (16 blocks x 256): W2 = softmax(alphas)*coeffs computed ONCE into
//    d_ws (bf16, B-fragment-linear order: frag (c,t) for lane l at element
//    c*2048 + t*512 + l*8). Replaces 256 redundant per-block computations.
//  - K2 (512 blocks x 256, 4 waves, Mt=2): barrier-free streaming GEMM.
//    NO __shared__, NO __syncthreads. B-fragments read directly from global
//    w2 (64 KB, L1/L2-resident; 1 KB contiguous per wave per read). Each
//    wave owns 32 rows (two 16-row tiles); 4 b-frags per K-step feed 8
//    MFMAs. x-loads / b-loads / trans-VALU / MFMA overlap freely across
//    8 waves/CU with no phase coupling.
//  - HW transcendentals: v_exp_f32 / v_log_f32 / v_sin_f32 / v_rcp_f32.
//    x in (0.5,1.5): no range reduction needed; err << bf16 rounding.
//  - C/D layout: col=lane&15, row=quad*4+reg (harness-verified in R5/R6).

typedef __bf16 bf16x8 __attribute__((ext_vector_type(8)));
typedef float f32x4 __attribute__((ext_vector_type(4)));

#define LOG2E   1.4426950408889634f
#define LN2     0.6931471805599453f
#define INV2PI  0.15915494309189535f

__device__ __forceinline__ bf16x8 prim_frag(float xv) {
    const float x2 = xv * xv;
    bf16x8 a;
    a[0] = (__bf16)0.0f;                                        // none
    a[1] = (__bf16)xv;                                          // linear
    a[2] = (__bf16)x2;                                          // x^2
    a[3] = (__bf16)(x2 * xv);                                   // x^3
    a[4] = (__bf16)__builtin_amdgcn_exp2f(xv * LOG2E);          // exp
    a[5] = (__bf16)(__builtin_amdgcn_logf(xv) * LN2);           // ln
    a[6] = (__bf16)__builtin_amdgcn_rcpf(xv);                   // 1/x
    a[7] = (__bf16)__builtin_amdgcn_sinf(xv * INV2PI);          // sin
    return a;
}

// ---- K1: W2 precompute, fragment-linear into workspace ---------------------
// gp = cc*256 + t*64 + qq*16 + nl  <->  unit (i = qq*16+cc, n = t*16+nl).
// One thread per unit; write = 16 B/thread, tid-contiguous (coalesced).
__global__ __launch_bounds__(256) void darts_w2(const float* __restrict__ alphas,
                                                const float* __restrict__ coeffs,
                                                __bf16* __restrict__ w2) {
    const int gp = blockIdx.x * 256 + threadIdx.x;      // 0..4095
    const int cc = gp >> 8;
    const int t  = (gp >> 6) & 3;
    const int qq = (gp >> 4) & 3;
    const int nl = gp & 15;
    const int src = ((qq * 16 + cc) * 64 + t * 16 + nl) * 8;
    const float* a  = alphas + src;
    const float* cf = coeffs + src;

    float e[8], s = 0.f;
#pragma unroll
    for (int k = 0; k < 8; ++k) {
        e[k] = __builtin_amdgcn_exp2f(a[k] * LOG2E);    // |a|<0.03: no max-sub
        s += e[k];
    }
    const float inv = __builtin_amdgcn_rcpf(s);

    bf16x8 w;
#pragma unroll
    for (int k = 0; k < 8; ++k) w[k] = (__bf16)(e[k] * inv * cf[k]);

    *(bf16x8*)(w2 + gp * 8) = w;
}

// ---- K2: barrier-free MFMA streaming kernel --------------------------------
__global__ __launch_bounds__(256, 2) void darts_mfma(const float* __restrict__ x,
                                                     const __bf16* __restrict__ w2,
                                                     float* __restrict__ out) {
    const int tid  = threadIdx.x;
    const int lane = tid & 63;
    const int wv   = tid >> 6;       // 0..3
    const int m    = lane & 15;      // A row within 16-tile
    const int q    = lane >> 4;      // quad

    // Wave wv owns rows base .. base+31 (two 16-row tiles).
    const int base = blockIdx.x * 128 + wv * 32;
    const float* xp0 = x + (base + m) * 64 + q * 16;
    f32x4 x00 = *(const f32x4*)(xp0 + 0);
    f32x4 x01 = *(const f32x4*)(xp0 + 4);
    f32x4 x02 = *(const f32x4*)(xp0 + 8);
    f32x4 x03 = *(const f32x4*)(xp0 + 12);
    const float* xp1 = xp0 + 16 * 64;                 // tile 1 = rows +16
    f32x4 x10 = *(const f32x4*)(xp1 + 0);
    f32x4 x11 = *(const f32x4*)(xp1 + 4);
    f32x4 x12 = *(const f32x4*)(xp1 + 8);
    f32x4 x13 = *(const f32x4*)(xp1 + 12);

    float xa0[16], xa1[16];
#pragma unroll
    for (int c = 0; c < 4; ++c) {
        xa0[c] = x00[c]; xa0[4 + c] = x01[c]; xa0[8 + c] = x02[c]; xa0[12 + c] = x03[c];
        xa1[c] = x10[c]; xa1[4 + c] = x11[c]; xa1[8 + c] = x12[c]; xa1[12 + c] = x13[c];
    }

    f32x4 acc00 = {0.f, 0.f, 0.f, 0.f}, acc01 = {0.f, 0.f, 0.f, 0.f};
    f32x4 acc02 = {0.f, 0.f, 0.f, 0.f}, acc03 = {0.f, 0.f, 0.f, 0.f};
    f32x4 acc10 = {0.f, 0.f, 0.f, 0.f}, acc11 = {0.f, 0.f, 0.f, 0.f};
    f32x4 acc12 = {0.f, 0.f, 0.f, 0.f}, acc13 = {0.f, 0.f, 0.f, 0.f};

#pragma unroll
    for (int c = 0; c < 16; ++c) {
        bf16x8 a0 = prim_frag(xa0[c]);
        bf16x8 a1 = prim_frag(xa1[c]);
        // 1 KB contiguous per wave per load; w2 is 64 KB, L1/L2-hot.
        const __bf16* bb = w2 + c * 2048 + lane * 8;
        bf16x8 b0 = *(const bf16x8*)(bb);
        bf16x8 b1 = *(const bf16x8*)(bb + 512);
        bf16x8 b2 = *(const bf16x8*)(bb + 1024);
        bf16x8 b3 = *(const bf16x8*)(bb + 1536);
        acc00 = __builtin_amdgcn_mfma_f32_16x16x32_bf16(a0, b0, acc00, 0, 0, 0);
        acc10 = __builtin_amdgcn_mfma_f32_16x16x32_bf16(a1, b0, acc10, 0, 0, 0);
        acc01 = __builtin_amdgcn_mfma_f32_16x16x32_bf16(a0, b1, acc01, 0, 0, 0);
        acc11 = __builtin_amdgcn_mfma_f32_16x16x32_bf16(a1, b1, acc11, 0, 0, 0);
        acc02 = __builtin_amdgcn_mfma_f32_16x16x32_bf16(a0, b2, acc02, 0, 0, 0);
        acc12 = __builtin_amdgcn_mfma_f32_16x16x32_bf16(a1, b2, acc12, 0, 0, 0);
        acc03 = __builtin_amdgcn_mfma_f32_16x16x32_bf16(a0, b3, acc03, 0, 0, 0);
        acc13 = __builtin_amdgcn_mfma_f32_16x16x32_bf16(a1, b3, acc13, 0, 0, 0);
    }

    // ---- epilogue: C layout col=lane&15, row=q*4+r (per tile) ---------------
    float* o0 = out + (base + q * 4) * 64 + m;
    float* o1 = o0 + 16 * 64;
#pragma unroll
    for (int r = 0; r < 4; ++r) {
        o0[r * 64 + 0]  = acc00[r];
        o0[r * 64 + 16] = acc01[r];
        o0[r * 64 + 32] = acc02[r];
        o0[r * 64 + 48] = acc03[r];
        o1[r * 64 + 0]  = acc10[r];
        o1[r * 64 + 16] = acc11[r];
        o1[r * 64 + 32] = acc12[r];
        o1[r * 64 + 48] = acc13[r];
    }
}

extern "C" void kernel_launch(void* const* d_in, const int* in_sizes, int n_in,
                              void* d_out, int out_size, void* d_ws, size_t ws_size,
                              hipStream_t stream) {
    const float* x      = (const float*)d_in[0];
    const float* alphas = (const float*)d_in[1];
    const float* coeffs = (const float*)d_in[2];
    float* out = (float*)d_out;
    __bf16* w2 = (__bf16*)d_ws;     // 64 KB of workspace (ws_size >> 64 KB)
    (void)ws_size;

    darts_w2<<<16, 256, 0, stream>>>(alphas, coeffs, w2);
    darts_mfma<<<512, 256, 0, stream>>>(x, w2, out);
}

// Round 3
// 80.281 us; speedup vs baseline: 1.0352x; 1.0352x over previous
//
#include <hip/hip_runtime.h>
#include <hip/hip_bf16.h>
#include <stdint.h>

// out[b,j] = sum_{i,k} softmax(alphas[i,j,:])[k] * coeffs[i,j,k] * prim_k(x[b,i])
//         == P @ W2,  P[b, kg] = prim_op(x[b,i]),  W2[kg][j]
// k-ordering remapped so the MFMA A-fragment is one cacheline/lane:
//   kg = c*32 + quad*8 + j  <->  i = quad*16 + c , op = j   (c=0..15, quad=0..3)
//
// R8: 2 BLOCKS/CU for cross-block phase overlap (sensitivity probe).
//  - 512 blocks x 512 threads (8 waves, 16 rows/wave, Mt=1). LDS 64 KB/block
//    -> 2 co-resident blocks/CU (128 KB of 160), 16 waves/CU = 4/SIMD.
//  - While block A is in its barrier-coupled W2-staging phase, co-resident
//    block B runs its MFMA phase: LDS port / VALU / trans / MFMA pipes stay
//    busy across barriers (R5 had 1 block/CU -> every barrier idled the CU).
//  - Phase B: 4096 units / 512 threads = 8 units each. LDS write LINEAR in
//    tid (conflict-free, R6 mapping); scatter on the global-read side
//    (32B-granule, tid-consecutive -> coalesced, L2/L3-hot).
//  - Tree-sum softmax (halves the fadd dependency chain). |alphas|<0.03:
//    max-subtraction skipped.
//  - HW transcendentals: v_exp_f32 / v_log_f32 / v_sin_f32 / v_rcp_f32.
//    x in (0.5,1.5): no range reduction needed; err << bf16 rounding.
//  - B reads: wlds + c*2048 + t*512 + lane*8 -> contiguous 1KB/wave
//    ds_read_b128, conflict-free.  C/D: col=lane&15, row=quad*4+reg
//    (harness-verified R5-R7).

typedef __bf16 bf16x8 __attribute__((ext_vector_type(8)));
typedef float f32x4 __attribute__((ext_vector_type(4)));

#define LOG2E   1.4426950408889634f
#define LN2     0.6931471805599453f
#define INV2PI  0.15915494309189535f

__global__ __launch_bounds__(512, 4) void darts_fused(const float* __restrict__ x,
                                                      const float* __restrict__ alphas,
                                                      const float* __restrict__ coeffs,
                                                      float* __restrict__ out) {
    __shared__ __bf16 wlds[32768];   // 64 KB, B-fragment order

    const int tid  = threadIdx.x;
    const int lane = tid & 63;
    const int wv   = tid >> 6;       // 0..7
    const int m    = lane & 15;      // A row within 16-tile
    const int q    = lane >> 4;      // quad

    // ---- phase A: issue x loads first (HBM latency hides behind phase B) ----
    const int row = blockIdx.x * 128 + wv * 16 + m;
    const float* xp = x + row * 64 + q * 16;
    f32x4 xr0 = *(const f32x4*)(xp + 0);
    f32x4 xr1 = *(const f32x4*)(xp + 4);
    f32x4 xr2 = *(const f32x4*)(xp + 8);
    f32x4 xr3 = *(const f32x4*)(xp + 12);

    // ---- phase B: W2 = softmax(alphas)*coeffs -> LDS (bf16, frag order) -----
    // Linear fragment position gp; LDS write tid-contiguous (conflict-free).
    //   gp = cc*256 + t*64 + qq*16 + nl ; unit (i = qq*16+cc, n = t*16+nl)
#pragma unroll
    for (int u = 0; u < 8; ++u) {
        const int gp = u * 512 + tid;
        const int cc = gp >> 8;
        const int t  = (gp >> 6) & 3;
        const int qq = (gp >> 4) & 3;
        const int nl = gp & 15;
        const int src = ((qq * 16 + cc) * 64 + t * 16 + nl) * 8;
        const float* a  = alphas + src;
        const float* cf = coeffs + src;

        float e[8];
#pragma unroll
        for (int k = 0; k < 8; ++k)
            e[k] = __builtin_amdgcn_exp2f(a[k] * LOG2E);   // |a|<0.03: no max-sub
        // tree sum: depth 3 instead of 7
        const float s01 = e[0] + e[1], s23 = e[2] + e[3];
        const float s45 = e[4] + e[5], s67 = e[6] + e[7];
        const float s = (s01 + s23) + (s45 + s67);
        const float inv = __builtin_amdgcn_rcpf(s);

        bf16x8 w;
#pragma unroll
        for (int k = 0; k < 8; ++k) w[k] = (__bf16)(e[k] * inv * cf[k]);

        *(bf16x8*)(wlds + gp * 8) = w;                     // linear: no conflicts
    }
    __syncthreads();

    // ---- phase C: MFMA main loop (Mt=1, 16 rows/wave) ----------------------
    float xa[16];
#pragma unroll
    for (int c = 0; c < 4; ++c) { xa[c] = xr0[c]; xa[4+c] = xr1[c]; xa[8+c] = xr2[c]; xa[12+c] = xr3[c]; }

    f32x4 acc0 = {0.f, 0.f, 0.f, 0.f};
    f32x4 acc1 = {0.f, 0.f, 0.f, 0.f};
    f32x4 acc2 = {0.f, 0.f, 0.f, 0.f};
    f32x4 acc3 = {0.f, 0.f, 0.f, 0.f};

#pragma unroll
    for (int c = 0; c < 16; ++c) {
        const float xv = xa[c];
        const float x2 = xv * xv;
        bf16x8 a;
        a[0] = (__bf16)0.0f;                                        // none
        a[1] = (__bf16)xv;                                          // linear
        a[2] = (__bf16)x2;                                          // x^2
        a[3] = (__bf16)(x2 * xv);                                   // x^3
        a[4] = (__bf16)__builtin_amdgcn_exp2f(xv * LOG2E);          // exp
        a[5] = (__bf16)(__builtin_amdgcn_logf(xv) * LN2);           // ln
        a[6] = (__bf16)__builtin_amdgcn_rcpf(xv);                   // 1/x
        a[7] = (__bf16)__builtin_amdgcn_sinf(xv * INV2PI);          // sin
        const __bf16* bb = wlds + c * 2048 + lane * 8;
        bf16x8 b0 = *(const bf16x8*)(bb);
        bf16x8 b1 = *(const bf16x8*)(bb + 512);
        bf16x8 b2 = *(const bf16x8*)(bb + 1024);
        bf16x8 b3 = *(const bf16x8*)(bb + 1536);
        acc0 = __builtin_amdgcn_mfma_f32_16x16x32_bf16(a, b0, acc0, 0, 0, 0);
        acc1 = __builtin_amdgcn_mfma_f32_16x16x32_bf16(a, b1, acc1, 0, 0, 0);
        acc2 = __builtin_amdgcn_mfma_f32_16x16x32_bf16(a, b2, acc2, 0, 0, 0);
        acc3 = __builtin_amdgcn_mfma_f32_16x16x32_bf16(a, b3, acc3, 0, 0, 0);
    }

    // ---- epilogue: C layout col=lane&15, row=q*4+r -------------------------
    float* orow = out + (blockIdx.x * 128 + wv * 16 + q * 4) * 64 + m;
#pragma unroll
    for (int r = 0; r < 4; ++r) {
        orow[r * 64 + 0]  = acc0[r];
        orow[r * 64 + 16] = acc1[r];
        orow[r * 64 + 32] = acc2[r];
        orow[r * 64 + 48] = acc3[r];
    }
}

extern "C" void kernel_launch(void* const* d_in, const int* in_sizes, int n_in,
                              void* d_out, int out_size, void* d_ws, size_t ws_size,
                              hipStream_t stream) {
    const float* x      = (const float*)d_in[0];
    const float* alphas = (const float*)d_in[1];
    const float* coeffs = (const float*)d_in[2];
    float* out = (float*)d_out;
    (void)d_ws; (void)ws_size;

    darts_fused<<<512, 512, 0, stream>>>(x, alphas, coeffs, out);
}

// Round 4
// 77.527 us; speedup vs baseline: 1.0720x; 1.0355x over previous
//
#include <hip/hip_runtime.h>
#include <hip/hip_bf16.h>
#include <stdint.h>

// out[b,j] = sum_{i,k} softmax(alphas[i,j,:])[k] * coeffs[i,j,k] * prim_k(x[b,i])
//         == P @ W2,  P[b, kg] = prim_op(x[b,i]),  W2[kg][j]
// k-ordering remapped so the MFMA A-fragment is one cacheline/lane:
//   kg = c*32 + quad*8 + j  <->  i = quad*16 + c , op = j   (c=0..15, quad=0..3)
//
// R9 = R5 REVERT (empirical best, 76.2 us). Session conclusion:
//  R5 76.2 | R6 (half LDS traffic) 78.3 | R7 (2-kernel, no barrier) 83.1 |
//  R8 (2 blk/CU overlap) 80.3 — wall time is insensitive to kernel structure;
//  it is dominated by the harness poison-fill (268 MB @ 77% HBM peak = 44 us,
//  already at the memory roofline) + fixed per-dispatch reset overhead.
//  The compute kernel term is ~10 us, within 2x of its own 5.6 us HBM floor;
//  every attempt to shrink it further cost more in launch/occupancy overhead
//  than it saved.
//
// Structure (R5): ONE kernel, 256 blocks x 1024 threads (1 block/CU, 16 waves).
//  - Each block: 256 rows; wave w: rows w*16..w*16+15, all 64 cols.
//  - W2 built per block into LDS (B-fragment order). Softmax max-sub skipped
//    (|alphas|<0.03 -> exp range [0.97,1.03], no overflow risk).
//  - HW transcendentals: v_exp_f32 / v_log_f32 / v_sin_f32 / v_rcp_f32.
//    x in (0.5,1.5) -> no range reduction needed; err << bf16 rounding.
//  - A-side prims in registers (lane (m,q) owns x[row m][16q..16q+15]).
//  - B reads: wlds + c*2048 + t*512 + lane*8 -> contiguous 1KB/wave
//    ds_read_b128, conflict-free.  C/D: col=lane&15, row=quad*4+reg.

typedef __bf16 bf16x8 __attribute__((ext_vector_type(8)));
typedef float f32x4 __attribute__((ext_vector_type(4)));

#define LOG2E   1.4426950408889634f
#define LN2     0.6931471805599453f
#define INV2PI  0.15915494309189535f

__global__ __launch_bounds__(1024, 4) void darts_fused(const float* __restrict__ x,
                                                       const float* __restrict__ alphas,
                                                       const float* __restrict__ coeffs,
                                                       float* __restrict__ out) {
    __shared__ __bf16 wlds[32768];   // 64 KB, B-fragment order

    const int tid  = threadIdx.x;
    const int lane = tid & 63;
    const int wv   = tid >> 6;       // 0..15
    const int m    = lane & 15;      // A row within 16-tile
    const int q    = lane >> 4;      // quad

    // ---- phase A: issue x loads first (HBM latency hides behind phase B) ----
    const int row = blockIdx.x * 256 + wv * 16 + m;
    const float* xp = x + row * 64 + q * 16;
    f32x4 xr0 = *(const f32x4*)(xp + 0);
    f32x4 xr1 = *(const f32x4*)(xp + 4);
    f32x4 xr2 = *(const f32x4*)(xp + 8);
    f32x4 xr3 = *(const f32x4*)(xp + 12);

    // ---- phase B: W2 = softmax(alphas)*coeffs -> LDS (bf16, frag order) -----
    // 4096 units / 1024 threads = 4 each; consecutive tids read consecutive
    // 32B chunks of alphas/coeffs (coalesced, L2/L3-hot after first blocks).
#pragma unroll
    for (int u = 0; u < 4; ++u) {
        const int g = u * 1024 + tid;       // g = i*64 + n
        const int i = g >> 6;
        const int n = g & 63;
        const float* a  = alphas + g * 8;
        const float* cf = coeffs + g * 8;

        float e[8], s = 0.f;
#pragma unroll
        for (int k = 0; k < 8; ++k) {
            e[k] = __builtin_amdgcn_exp2f(a[k] * LOG2E);   // |a|<0.03: no max-sub
            s += e[k];
        }
        const float inv = __builtin_amdgcn_rcpf(s);

        bf16x8 w;
#pragma unroll
        for (int k = 0; k < 8; ++k) w[k] = (__bf16)(e[k] * inv * cf[k]);

        // i = quad*16 + step ; n = tile*16 + nl  -> fragment-order position
        const int qq = i >> 4, cc = i & 15, t = n >> 4, nl = n & 15;
        *(bf16x8*)(wlds + ((cc * 4 + t) * 64 + qq * 16 + nl) * 8) = w;
    }
    __syncthreads();

    // ---- phase C: MFMA main loop -------------------------------------------
    float xa[16];
#pragma unroll
    for (int c = 0; c < 4; ++c) { xa[c] = xr0[c]; xa[4+c] = xr1[c]; xa[8+c] = xr2[c]; xa[12+c] = xr3[c]; }

    f32x4 acc0 = {0.f, 0.f, 0.f, 0.f};
    f32x4 acc1 = {0.f, 0.f, 0.f, 0.f};
    f32x4 acc2 = {0.f, 0.f, 0.f, 0.f};
    f32x4 acc3 = {0.f, 0.f, 0.f, 0.f};

#pragma unroll
    for (int c = 0; c < 16; ++c) {
        const float xv = xa[c];
        const float x2 = xv * xv;
        bf16x8 a;
        a[0] = (__bf16)0.0f;                                        // none
        a[1] = (__bf16)xv;                                          // linear
        a[2] = (__bf16)x2;                                          // x^2
        a[3] = (__bf16)(x2 * xv);                                   // x^3
        a[4] = (__bf16)__builtin_amdgcn_exp2f(xv * LOG2E);          // exp
        a[5] = (__bf16)(__builtin_amdgcn_logf(xv) * LN2);           // ln
        a[6] = (__bf16)__builtin_amdgcn_rcpf(xv);                   // 1/x
        a[7] = (__bf16)__builtin_amdgcn_sinf(xv * INV2PI);          // sin
        const __bf16* bb = wlds + c * 2048 + lane * 8;
        bf16x8 b0 = *(const bf16x8*)(bb);
        bf16x8 b1 = *(const bf16x8*)(bb + 512);
        bf16x8 b2 = *(const bf16x8*)(bb + 1024);
        bf16x8 b3 = *(const bf16x8*)(bb + 1536);
        acc0 = __builtin_amdgcn_mfma_f32_16x16x32_bf16(a, b0, acc0, 0, 0, 0);
        acc1 = __builtin_amdgcn_mfma_f32_16x16x32_bf16(a, b1, acc1, 0, 0, 0);
        acc2 = __builtin_amdgcn_mfma_f32_16x16x32_bf16(a, b2, acc2, 0, 0, 0);
        acc3 = __builtin_amdgcn_mfma_f32_16x16x32_bf16(a, b3, acc3, 0, 0, 0);
    }

    // ---- epilogue: C layout col=lane&15, row=q*4+r -------------------------
    float* orow = out + (blockIdx.x * 256 + wv * 16 + q * 4) * 64 + m;
#pragma unroll
    for (int r = 0; r < 4; ++r) {
        orow[r * 64 + 0]  = acc0[r];
        orow[r * 64 + 16] = acc1[r];
        orow[r * 64 + 32] = acc2[r];
        orow[r * 64 + 48] = acc3[r];
    }
}

extern "C" void kernel_launch(void* const* d_in, const int* in_sizes, int n_in,
                              void* d_out, int out_size, void* d_ws, size_t ws_size,
                              hipStream_t stream) {
    const float* x      = (const float*)d_in[0];
    const float* alphas = (const float*)d_in[1];
    const float* coeffs = (const float*)d_in[2];
    float* out = (float*)d_out;
    (void)d_ws; (void)ws_size;

    darts_fused<<<256, 1024, 0, stream>>>(x, alphas, coeffs, out);
}